// Round 9
// baseline (680.487 us; speedup 1.0000x reference)
//
#include <hip/hip_runtime.h>
#include <cstdint>
#include <cstddef>

#define N_NODES 10000
#define N_EDGES 320000
#define N_GRAPHS 64
#define KCHEB 10
#define C_IN 128
#define C_HID 256
#define C_OUTC 128

static inline size_t align_up(size_t v, size_t a){ return (v + a - 1) / a * a; }

typedef __attribute__((ext_vector_type(8))) _Float16 half8;
typedef __attribute__((ext_vector_type(2))) _Float16 h2;
typedef __attribute__((ext_vector_type(4))) float f32x4;

// ---------------- graph setup kernels ----------------

__global__ void k_deg(const int* __restrict__ src, const int* __restrict__ dst,
                      int* __restrict__ deg, int* __restrict__ indeg){
  int e = blockIdx.x*blockDim.x + threadIdx.x;
  if(e < N_EDGES){
    atomicAdd(&deg[src[e]], 1);
    atomicAdd(&indeg[dst[e]], 1);
  }
}

// scan(indeg)->offs/cursor, dis=rsqrt(deg), counting sort by in-degree
// (descending) -> perm, AND graph bounds (threads 0..64 binary-search batch).
__global__ __launch_bounds__(1024) void k_scan(const int* __restrict__ cnt,
                                               int* __restrict__ offs,
                                               int* __restrict__ cursor,
                                               const int* __restrict__ deg,
                                               float* __restrict__ dis,
                                               int* __restrict__ perm,
                                               const int* __restrict__ batch,
                                               int* __restrict__ gstart,
                                               int* __restrict__ gcnt){
  __shared__ int part[1024];
  __shared__ int hist[256];
  __shared__ int hoff[256];
  const int n = N_NODES;
  const int CH = (n + 1023) / 1024;
  int tid = threadIdx.x;
  int base = tid * CH;
  if(tid < 256) hist[tid] = 0;
  if(tid <= N_GRAPHS){
    int lo = 0, hi = N_NODES;
    while(lo < hi){
      int mid = (lo + hi) >> 1;
      if(batch[mid] < tid) lo = mid + 1; else hi = mid;
    }
    gstart[tid] = lo;
  }
  int s = 0;
  for(int i = 0; i < CH; i++){
    int idx = base + i;
    if(idx < n){
      s += cnt[idx];
      int d = deg[idx];
      dis[idx] = d > 0 ? rsqrtf((float)d) : 0.f;
    }
  }
  part[tid] = s;
  __syncthreads();
  if(tid < N_GRAPHS) gcnt[tid] = gstart[tid + 1] - gstart[tid];
  for(int off = 1; off < 1024; off <<= 1){
    int v = (tid >= off) ? part[tid - off] : 0;
    __syncthreads();
    part[tid] += v;
    __syncthreads();
  }
  int run = (tid == 0) ? 0 : part[tid - 1];
  for(int i = 0; i < CH; i++){
    int idx = base + i;
    if(idx < n){
      offs[idx] = run;
      cursor[idx] = run;
      run += cnt[idx];
      int d = cnt[idx]; if(d > 255) d = 255;
      atomicAdd(&hist[d], 1);
    }
  }
  if(tid == 1023) offs[n] = part[1023];
  __syncthreads();
  if(tid == 0){
    int r2 = 0;
    for(int d = 255; d >= 0; d--){ hoff[d] = r2; r2 += hist[d]; }
  }
  __syncthreads();
  for(int i = 0; i < CH; i++){
    int idx = base + i;
    if(idx < n){
      int d = cnt[idx]; if(d > 255) d = 255;
      int p0 = atomicAdd(&hoff[d], 1);
      perm[p0] = idx;
    }
  }
}

__global__ void k_scatter(const int* __restrict__ src, const int* __restrict__ dst,
                          const float* __restrict__ dis, int* __restrict__ cursor,
                          int* __restrict__ csr_s, unsigned* __restrict__ csr_wp){
  int e = blockIdx.x*blockDim.x + threadIdx.x;
  if(e < N_EDGES){
    int s = src[e], d = dst[e];
    float w = -dis[s] * dis[d];
    unsigned short wb = __builtin_bit_cast(unsigned short, (_Float16)w);
    int p = atomicAdd(&cursor[d], 1);
    csr_s[p] = s;
    csr_wp[p] = (unsigned)wb * 0x00010001u;
  }
}

// ---------------- propagation (f16, 64-ch pieces, L2-capacity-fitted) ------
// Unified kernel: channels split into NPIECE pieces of 64ch, each piece
// pinned to an XCD group via bid%8 (NPIECE=2: 4 XCDs/piece; NPIECE=4: 2
// XCDs/piece). Per-XCD hot gather set = 10000 nodes x 64ch x 2B = 1.28 MB;
// hot + streams (CSR/out/Pb) ~3.2 MB < 4 MB L2 (the 128-ch half split was
// ~4.5 MB -> stream evictions of the hot set). Gather = 16 lanes x 8B = one
// aligned 128B line per edge-piece, fetched only by the owning XCD pair.
// Single-buffer loop (round-7 proven; 2-deep pipeline regressed via VGPR).

template<int STRIDE, int NPIECE>
__global__ __launch_bounds__(256) void k_prop(const _Float16* __restrict__ Xb,
                                              const _Float16* __restrict__ Pb,
                                              _Float16* __restrict__ tx,
                                              const int* __restrict__ csr_s,
                                              const unsigned* __restrict__ csr_wp,
                                              const int* __restrict__ offs,
                                              const int* __restrict__ perm,
                                              float alpha){
  const int strideB = STRIDE * 2;
  int bid = blockIdx.x;
  int piece, lh;
  if(NPIECE == 2){ piece = (bid >> 2) & 1; lh = (bid >> 3) * 4 + (bid & 3); }
  else           { piece = (bid >> 1) & 3; lh = (bid >> 3) * 2 + (bid & 1); }
  int l15  = threadIdx.x & 15;
  int lane = threadIdx.x & 63;
  int b16  = lane & 48;
  int e8   = l15 & 7;
  int nidx = lh * 16 + (threadIdx.x >> 4);
  if(nidx >= N_NODES) return;
  int node = perm[nidx];
  int j0 = offs[node], j1 = offs[node + 1];
  h2 a[2] = {};
  const char* __restrict__ gbase = (const char*)Xb + (piece * 64 + l15 * 4) * 2;
  int j = j0;
  int sv = 0; unsigned wv = 0;
  bool have = (j + 7 < j1);
  if(have){ sv = csr_s[j + e8] * strideB; wv = csr_wp[j + e8]; }
  while(have){
    int jn = j + 8;
    bool more = (jn + 7 < j1);
    int sv2 = 0; unsigned wv2 = 0;
    if(more){ sv2 = csr_s[jn + e8] * strideB; wv2 = csr_wp[jn + e8]; }
    uint2 v[8];
#pragma unroll
    for(int i = 0; i < 8; i++){
      int si = __shfl(sv, b16 + i);
      v[i] = *(const uint2*)(gbase + si);
    }
#pragma unroll
    for(int i = 0; i < 8; i++){
      unsigned wi = (unsigned)__shfl((int)wv, b16 + i);
      h2 w2 = __builtin_bit_cast(h2, wi);
      a[0] += __builtin_bit_cast(h2, v[i].x) * w2;
      a[1] += __builtin_bit_cast(h2, v[i].y) * w2;
    }
    sv = sv2; wv = wv2; j = jn; have = more;
  }
  for(; j < j1; j++){
    int si = csr_s[j] * strideB;
    h2 w2 = __builtin_bit_cast(h2, csr_wp[j]);
    uint2 v0 = *(const uint2*)(gbase + si);
    a[0] += __builtin_bit_cast(h2, v0.x) * w2;
    a[1] += __builtin_bit_cast(h2, v0.y) * w2;
  }
  _Float16 ah = (_Float16)alpha;
  h2 al = {ah, ah};
  h2 r0 = a[0] * al, r1 = a[1] * al;
  size_t off = (size_t)node * STRIDE + piece * 64 + l15 * 4;
  if(Pb){
    uint2 pv = *(const uint2*)(Pb + off);
    r0 -= __builtin_bit_cast(h2, pv.x);
    r1 -= __builtin_bit_cast(h2, pv.y);
  }
  uint2 ob;
  ob.x = __builtin_bit_cast(unsigned, r0);
  ob.y = __builtin_bit_cast(unsigned, r1);
  *(uint2*)(tx + off) = ob;
}

// ---------------- fused prep: weight transposes + x->f16 ----------------
__global__ __launch_bounds__(256) void k_prep(const float* __restrict__ W0, _Float16* __restrict__ WT0,
                                              const float* __restrict__ W1, _Float16* __restrict__ WT1,
                                              const float* __restrict__ W2, _Float16* __restrict__ WT2,
                                              const float* __restrict__ X, _Float16* __restrict__ txP){
  int b = blockIdx.x;
  if(b >= 1600){
    int idx = (b - 1600) * 256 + threadIdx.x;
    if(idx < N_NODES * (C_IN / 4)){
      int r = idx >> 5;                 // C_IN/4 = 32
      int c = (idx & 31) * 4;
      float4 v = *(const float4*)(X + (size_t)r * C_IN + c);
      h2 p0 = {(_Float16)v.x, (_Float16)v.y};
      h2 p1 = {(_Float16)v.z, (_Float16)v.w};
      uint2 ob;
      ob.x = __builtin_bit_cast(unsigned, p0);
      ob.y = __builtin_bit_cast(unsigned, p1);
      *(uint2*)(txP + (size_t)r * (KCHEB * C_IN) + c) = ob;
    }
    return;
  }
  __shared__ float t[32][33];
  const float* W; _Float16* WT; int R; int tb;
  if(b < 320){ W = W0; WT = WT0; R = 1280; tb = b; }
  else if(b < 960){ W = W1; WT = WT1; R = 2560; tb = b - 320; }
  else { W = W2; WT = WT2; R = 2560; tb = b - 960; }
  int tr = tb >> 3, tc = tb & 7;
  int tx = threadIdx.x & 31, ty = threadIdx.x >> 5;
#pragma unroll
  for(int i = 0; i < 4; i++){
    int r = tr * 32 + ty + 8 * i;
    t[ty + 8 * i][tx] = W[(size_t)r * 256 + tc * 32 + tx];
  }
  __syncthreads();
#pragma unroll
  for(int i = 0; i < 4; i++){
    int o = tc * 32 + ty + 8 * i;
    WT[(size_t)o * R + tr * 32 + tx] = (_Float16)t[tx][ty + 8 * i];
  }
}

// ---------------- MFMA GEMM (f16) 64x64, XCD-pinned, single-sync dbuf ------
// PROVEN shape: 640 blocks, 32KB LDS, 0 bank conflicts. Layer-3 path
// (tx2==null): pooled epilogue (LDS-stage ReLU tile, run-reduce, atomicAdd).

__global__ __launch_bounds__(256) void k_gemm_f(const _Float16* __restrict__ A,
                                                const _Float16* __restrict__ BT,
                                                const float* __restrict__ bias,
                                                _Float16* __restrict__ tx2,
                                                const int* __restrict__ batch,
                                                float* __restrict__ gsum,
                                                int M, int Ktot){
  int b = blockIdx.x;
  int xcd = b & 7;
  int l = b >> 3;
  int m = xcd + 8 * (l >> 2);
  int n = l & 3;
  if(m * 64 >= M) return;
  int row0 = m * 64, col0 = n * 64;

  __shared__ short As[2][64 * 64];
  __shared__ short Bs[2][64 * 64];
  int tid = threadIdx.x;
  int lane = tid & 63;
  int wave = tid >> 6;
  int l15 = lane & 15;
  int quad = lane >> 4;
  int wm = (wave & 1) * 32;
  int wn = (wave >> 1) * 32;

  int e0 = tid, e1 = tid + 256;
  int r0 = e0 >> 3, g0 = e0 & 7;
  int r1 = e1 >> 3, g1 = e1 & 7;
  int gr0 = row0 + r0, gr1 = row0 + r1;
  int sa0 = r0 * 64 + ((g0 ^ (r0 & 7)) * 8);
  int sa1 = r1 * 64 + ((g1 ^ (r1 & 7)) * 8);

  f32x4 acc[2][2] = {};
  uint4 av0, av1, bv0, bv1;

  auto load = [&](int k0){
    av0 = (gr0 < M) ? *(const uint4*)(A + (size_t)gr0 * Ktot + k0 + g0 * 8)
                    : make_uint4(0u, 0u, 0u, 0u);
    av1 = (gr1 < M) ? *(const uint4*)(A + (size_t)gr1 * Ktot + k0 + g1 * 8)
                    : make_uint4(0u, 0u, 0u, 0u);
    bv0 = *(const uint4*)(BT + (size_t)(col0 + r0) * Ktot + k0 + g0 * 8);
    bv1 = *(const uint4*)(BT + (size_t)(col0 + r1) * Ktot + k0 + g1 * 8);
  };
  auto stor = [&](int buf){
    *(uint4*)(&As[buf][sa0]) = av0;
    *(uint4*)(&As[buf][sa1]) = av1;
    *(uint4*)(&Bs[buf][sa0]) = bv0;
    *(uint4*)(&Bs[buf][sa1]) = bv1;
  };

  load(0);
  stor(0);
  __syncthreads();
  int nk = Ktot >> 6;
  for(int it = 0; it < nk; it++){
    int cur = it & 1;
    if(it + 1 < nk) load((it + 1) << 6);   // in flight across MFMAs
#pragma unroll
    for(int kk = 0; kk < 64; kk += 32){
      int g = (kk >> 3) + quad;
      half8 a[2], bb[2];
#pragma unroll
      for(int mi = 0; mi < 2; mi++){
        int r = wm + mi * 16 + l15;
        a[mi] = *(const half8*)(&As[cur][r * 64 + ((g ^ (r & 7)) * 8)]);
      }
#pragma unroll
      for(int ni = 0; ni < 2; ni++){
        int nn = wn + ni * 16 + l15;
        bb[ni] = *(const half8*)(&Bs[cur][nn * 64 + ((g ^ (nn & 7)) * 8)]);
      }
#pragma unroll
      for(int mi = 0; mi < 2; mi++)
#pragma unroll
        for(int ni = 0; ni < 2; ni++)
          acc[mi][ni] = __builtin_amdgcn_mfma_f32_16x16x32_f16(a[mi], bb[ni], acc[mi][ni], 0, 0, 0);
    }
    if(it + 1 < nk){
      stor(cur ^ 1);
      __syncthreads();
    }
  }

  if(tx2){
    const int K256 = KCHEB * C_HID;
#pragma unroll
    for(int mi = 0; mi < 2; mi++){
#pragma unroll
      for(int ni = 0; ni < 2; ni++){
        int gcol = col0 + wn + ni * 16 + l15;
        float bv = bias[gcol];
#pragma unroll
        for(int r = 0; r < 4; r++){
          int grow = row0 + wm + mi * 16 + quad * 4 + r;
          if(grow < M){
            float v = fmaxf(acc[mi][ni][r] + bv, 0.f);
            tx2[(size_t)grow * K256 + gcol] = (_Float16)v;
          }
        }
      }
    }
  } else {
    // pooled epilogue (layer 3)
    __syncthreads();
    float* Ls = (float*)As;                // 16 KB
#pragma unroll
    for(int mi = 0; mi < 2; mi++){
#pragma unroll
      for(int ni = 0; ni < 2; ni++){
        int lc = wn + ni * 16 + l15;
        float bv = bias[col0 + lc];
#pragma unroll
        for(int r = 0; r < 4; r++){
          int lr = wm + mi * 16 + quad * 4 + r;
          Ls[lr * 64 + lc] = fmaxf(acc[mi][ni][r] + bv, 0.f);
        }
      }
    }
    __syncthreads();
    int col  = tid & 63;
    int rseg = tid >> 6;
    int rb   = rseg * 16;
    float accp = 0.f;
    int curg = -1;
    for(int rr = 0; rr < 16; rr++){
      int grow = row0 + rb + rr;
      if(grow >= M) break;
      int g = batch[grow];
      if(g != curg){
        if(curg >= 0) atomicAdd(&gsum[curg * C_HID + col0 + col], accp);
        accp = 0.f; curg = g;
      }
      accp += Ls[(rb + rr) * 64 + col];
    }
    if(curg >= 0) atomicAdd(&gsum[curg * C_HID + col0 + col], accp);
  }
}

// ---------------- head ----------------

__global__ __launch_bounds__(128) void k_final(const float* __restrict__ gsum,
                                               const int* __restrict__ gcnt,
                                               const float* __restrict__ Wout,
                                               const float* __restrict__ bout,
                                               float* __restrict__ out){
  int g = blockIdx.x;
  int o = threadIdx.x;
  float inv = 1.f / fmaxf((float)gcnt[g], 1.f);
  float acc = bout[o];
  for(int c = 0; c < C_HID; c++) acc += gsum[g * C_HID + c] * inv * Wout[c * C_OUTC + o];
  out[g * C_OUTC + o] = acc;
}

// ---------------- host ----------------

extern "C" void kernel_launch(void* const* d_in, const int* in_sizes, int n_in,
                              void* d_out, int out_size, void* d_ws, size_t ws_size,
                              hipStream_t stream){
  const float* x    = (const float*)d_in[0];
  const float* W0   = (const float*)d_in[1];
  const float* b0   = (const float*)d_in[2];
  const float* W1   = (const float*)d_in[3];
  const float* b1   = (const float*)d_in[4];
  const float* W2   = (const float*)d_in[5];
  const float* b2   = (const float*)d_in[6];
  const float* Wout = (const float*)d_in[7];
  const float* bout = (const float*)d_in[8];
  const int*   ei   = (const int*)d_in[9];
  const int*   batch= (const int*)d_in[10];
  const int* src = ei;
  const int* dst = ei + N_EDGES;
  float* out = (float*)d_out;

  char* p = (char*)d_ws;
  auto alloc = [&](size_t bytes)->char*{ char* r = p; p += align_up(bytes, 256); return r; };

  int*   deg    = (int*)  alloc(N_NODES * 4);
  int*   indeg  = (int*)  alloc(N_NODES * 4);
  int*   offs   = (int*)  alloc((N_NODES + 1) * 4);
  int*   cursor = (int*)  alloc(N_NODES * 4);
  float* dis    = (float*)alloc(N_NODES * 4);
  int*   perm   = (int*)  alloc(N_NODES * 4);
  int*   csr_s  = (int*)  alloc(N_EDGES * 4);
  unsigned* csr_wp = (unsigned*)alloc(N_EDGES * 4);
  int*   gcnt   = (int*)  alloc(N_GRAPHS * 4);
  int*   gstart = (int*)  alloc((N_GRAPHS + 1) * 4);
  float* gsum   = (float*)alloc(N_GRAPHS * C_HID * 4);

  const size_t txBytes = (size_t)N_NODES * (KCHEB * C_HID) * 2;  // 51.2 MB
  _Float16* txP = (_Float16*)alloc(txBytes);
  _Float16* txQ = (_Float16*)alloc(txBytes);
  _Float16* WT0 = (_Float16*)alloc((size_t)KCHEB * C_IN  * C_HID * 2);
  _Float16* WT1 = (_Float16*)alloc((size_t)KCHEB * C_HID * C_HID * 2);
  _Float16* WT2 = (_Float16*)alloc((size_t)KCHEB * C_HID * C_HID * 2);

  hipMemsetAsync(deg,   0, N_NODES * 4, stream);
  hipMemsetAsync(indeg, 0, N_NODES * 4, stream);
  hipMemsetAsync(gsum,  0, N_GRAPHS * C_HID * 4, stream);

  const int TB = 256;
  int egrid = (N_EDGES + TB - 1) / TB;

  k_deg<<<egrid, TB, 0, stream>>>(src, dst, deg, indeg);
  k_scan<<<1, 1024, 0, stream>>>(indeg, offs, cursor, deg, dis, perm, batch, gstart, gcnt);
  k_scatter<<<egrid, TB, 0, stream>>>(src, dst, dis, cursor, csr_s, csr_wp);
  k_prep<<<2850, 256, 0, stream>>>(W0, WT0, W1, WT1, W2, WT2, x, txP);

  const int K128 = KCHEB * C_IN;   // 1280
  const int K256 = KCHEB * C_HID;  // 2560
  const int GEMM_BLOCKS = 640;
  // NPIECE=2: lh=(bid>>3)*4+(bid&3) must reach 624 -> 157*8 = 1256 blocks
  // NPIECE=4: lh=(bid>>3)*2+(bid&1) must reach 624 -> 313*8 = 2504 blocks
  const int PROP2_BLOCKS = 1256;
  const int PROP4_BLOCKS = 2504;

  // ---- layer 1 (64-ch pieces, 2 pieces, 4 XCDs each) ----
  {
    for(int k = 1; k < KCHEB; k++){
      const _Float16* Xb = txP + (size_t)(k - 1) * C_IN;
      const _Float16* Pb = (k >= 2) ? txP + (size_t)(k - 2) * C_IN : nullptr;
      _Float16* tx = txP + (size_t)k * C_IN;
      k_prop<K128, 2><<<PROP2_BLOCKS, 256, 0, stream>>>(Xb, Pb, tx, csr_s, csr_wp, offs, perm,
                                                        k == 1 ? 1.f : 2.f);
    }
    k_gemm_f<<<GEMM_BLOCKS, 256, 0, stream>>>(txP, WT0, b0, txQ, nullptr, nullptr,
                                              N_NODES, K128);
  }

  // ---- layer 2 (64-ch pieces, 4 pieces, 2 XCDs each) ----
  {
    for(int k = 1; k < KCHEB; k++){
      const _Float16* Xb = txQ + (size_t)(k - 1) * C_HID;
      const _Float16* Pb = (k >= 2) ? txQ + (size_t)(k - 2) * C_HID : nullptr;
      _Float16* tx = txQ + (size_t)k * C_HID;
      k_prop<K256, 4><<<PROP4_BLOCKS, 256, 0, stream>>>(Xb, Pb, tx, csr_s, csr_wp, offs, perm,
                                                        k == 1 ? 1.f : 2.f);
    }
    k_gemm_f<<<GEMM_BLOCKS, 256, 0, stream>>>(txQ, WT1, b1, txP, nullptr, nullptr,
                                              N_NODES, K256);
  }

  // ---- layer 3 ----
  {
    for(int k = 1; k < KCHEB; k++){
      const _Float16* Xb = txP + (size_t)(k - 1) * C_HID;
      const _Float16* Pb = (k >= 2) ? txP + (size_t)(k - 2) * C_HID : nullptr;
      _Float16* tx = txP + (size_t)k * C_HID;
      k_prop<K256, 4><<<PROP4_BLOCKS, 256, 0, stream>>>(Xb, Pb, tx, csr_s, csr_wp, offs, perm,
                                                        k == 1 ? 1.f : 2.f);
    }
    k_gemm_f<<<GEMM_BLOCKS, 256, 0, stream>>>(txP, WT2, b2, nullptr, batch, gsum,
                                              N_NODES, K256);
  }

  k_final<<<N_GRAPHS, C_OUTC, 0, stream>>>(gsum, gcnt, Wout, bout, out);
}

// Round 11
// 612.651 us; speedup vs baseline: 1.1107x; 1.1107x over previous
//
#include <hip/hip_runtime.h>
#include <cstdint>
#include <cstddef>

#define N_NODES 10000
#define N_EDGES 320000
#define N_GRAPHS 64
#define KCHEB 10
#define C_IN 128
#define C_HID 256
#define C_OUTC 128

static inline size_t align_up(size_t v, size_t a){ return (v + a - 1) / a * a; }

typedef __attribute__((ext_vector_type(8))) _Float16 half8;
typedef __attribute__((ext_vector_type(2))) _Float16 h2;
typedef __attribute__((ext_vector_type(4))) float f32x4;

// ---------------- graph setup kernels ----------------

__global__ void k_deg(const int* __restrict__ src, const int* __restrict__ dst,
                      int* __restrict__ deg, int* __restrict__ indeg){
  int e = blockIdx.x*blockDim.x + threadIdx.x;
  if(e < N_EDGES){
    atomicAdd(&deg[src[e]], 1);
    atomicAdd(&indeg[dst[e]], 1);
  }
}

// scan(indeg)->offs/cursor, dis=rsqrt(deg), counting sort by in-degree
// (descending) -> perm, AND graph bounds (threads 0..64 binary-search batch).
__global__ __launch_bounds__(1024) void k_scan(const int* __restrict__ cnt,
                                               int* __restrict__ offs,
                                               int* __restrict__ cursor,
                                               const int* __restrict__ deg,
                                               float* __restrict__ dis,
                                               int* __restrict__ perm,
                                               const int* __restrict__ batch,
                                               int* __restrict__ gstart,
                                               int* __restrict__ gcnt){
  __shared__ int part[1024];
  __shared__ int hist[256];
  __shared__ int hoff[256];
  const int n = N_NODES;
  const int CH = (n + 1023) / 1024;
  int tid = threadIdx.x;
  int base = tid * CH;
  if(tid < 256) hist[tid] = 0;
  if(tid <= N_GRAPHS){
    int lo = 0, hi = N_NODES;
    while(lo < hi){
      int mid = (lo + hi) >> 1;
      if(batch[mid] < tid) lo = mid + 1; else hi = mid;
    }
    gstart[tid] = lo;
  }
  int s = 0;
  for(int i = 0; i < CH; i++){
    int idx = base + i;
    if(idx < n){
      s += cnt[idx];
      int d = deg[idx];
      dis[idx] = d > 0 ? rsqrtf((float)d) : 0.f;
    }
  }
  part[tid] = s;
  __syncthreads();
  if(tid < N_GRAPHS) gcnt[tid] = gstart[tid + 1] - gstart[tid];
  for(int off = 1; off < 1024; off <<= 1){
    int v = (tid >= off) ? part[tid - off] : 0;
    __syncthreads();
    part[tid] += v;
    __syncthreads();
  }
  int run = (tid == 0) ? 0 : part[tid - 1];
  for(int i = 0; i < CH; i++){
    int idx = base + i;
    if(idx < n){
      offs[idx] = run;
      cursor[idx] = run;
      run += cnt[idx];
      int d = cnt[idx]; if(d > 255) d = 255;
      atomicAdd(&hist[d], 1);
    }
  }
  if(tid == 1023) offs[n] = part[1023];
  __syncthreads();
  if(tid == 0){
    int r2 = 0;
    for(int d = 255; d >= 0; d--){ hoff[d] = r2; r2 += hist[d]; }
  }
  __syncthreads();
  for(int i = 0; i < CH; i++){
    int idx = base + i;
    if(idx < n){
      int d = cnt[idx]; if(d > 255) d = 255;
      int p0 = atomicAdd(&hoff[d], 1);
      perm[p0] = idx;
    }
  }
}

__global__ void k_scatter(const int* __restrict__ src, const int* __restrict__ dst,
                          const float* __restrict__ dis, int* __restrict__ cursor,
                          int* __restrict__ csr_s, unsigned* __restrict__ csr_wp){
  int e = blockIdx.x*blockDim.x + threadIdx.x;
  if(e < N_EDGES){
    int s = src[e], d = dst[e];
    float w = -dis[s] * dis[d];
    unsigned short wb = __builtin_bit_cast(unsigned short, (_Float16)w);
    int p = atomicAdd(&cursor[d], 1);
    csr_s[p] = s;
    csr_wp[p] = (unsigned)wb * 0x00010001u;
  }
}

// ---------------- propagation (f16 state, v_pk_fma_f16, degree-sorted) -----
// PROVEN round-7 configuration: half-split uint4 gathers, single-buffer loop.
// (2-deep pipeline: falsified r8, -43us via VGPR pressure. 4-way 64-ch split:
// falsified r9, -65us via smaller transactions + doubled grid.)

__device__ inline void hfma4(h2* a, uint4 v, unsigned wbits){
  h2 w2 = __builtin_bit_cast(h2, wbits);
  a[0] += __builtin_bit_cast(h2, v.x) * w2;
  a[1] += __builtin_bit_cast(h2, v.y) * w2;
  a[2] += __builtin_bit_cast(h2, v.z) * w2;
  a[3] += __builtin_bit_cast(h2, v.w) * w2;
}

// 256-ch, channel-split halves pinned to XCD groups (bid%8 -> XCD; 0-3 =
// half0, 4-7 = half1): per-XCD gather working set 2.56 MB. 16-lane groups
// own one node-half; degree-sorted perm kills max-of-N divergence.
__global__ __launch_bounds__(256) void k_prop256h(const _Float16* __restrict__ Xb,
                                                  const _Float16* __restrict__ Pb,
                                                  _Float16* __restrict__ tx,
                                                  const int* __restrict__ csr_s,
                                                  const unsigned* __restrict__ csr_wp,
                                                  const int* __restrict__ offs,
                                                  const int* __restrict__ perm,
                                                  float alpha){
  const int stride  = KCHEB * C_HID;
  const int strideB = stride * 2;        // 5120 bytes
  int bid  = blockIdx.x;
  int half = (bid >> 2) & 1;
  int lh   = (bid >> 3) * 4 + (bid & 3);
  int l15  = threadIdx.x & 15;
  int lane = threadIdx.x & 63;
  int b16  = lane & 48;
  int e8   = l15 & 7;
  int nidx = lh * 16 + (threadIdx.x >> 4);
  if(nidx >= N_NODES) return;
  int node = perm[nidx];
  int j0 = offs[node], j1 = offs[node + 1];
  h2 a[4] = {};
  const char* __restrict__ gbase = (const char*)Xb + (half * (C_HID/2) + l15 * 8) * 2;
  int j = j0;
  int sv = 0; unsigned wv = 0;
  bool have = (j + 7 < j1);
  if(have){ sv = csr_s[j + e8] * strideB; wv = csr_wp[j + e8]; }
  while(have){
    int jn = j + 8;
    bool more = (jn + 7 < j1);
    int sv2 = 0; unsigned wv2 = 0;
    if(more){ sv2 = csr_s[jn + e8] * strideB; wv2 = csr_wp[jn + e8]; }
    uint4 v[8];
#pragma unroll
    for(int i = 0; i < 8; i++){
      int si = __shfl(sv, b16 + i);
      v[i] = *(const uint4*)(gbase + si);
    }
#pragma unroll
    for(int i = 0; i < 8; i++){
      unsigned wi = (unsigned)__shfl((int)wv, b16 + i);
      hfma4(a, v[i], wi);
    }
    sv = sv2; wv = wv2; j = jn; have = more;
  }
  for(; j < j1; j++){
    int si = csr_s[j] * strideB;
    uint4 v0 = *(const uint4*)(gbase + si);
    hfma4(a, v0, csr_wp[j]);
  }
  _Float16 ah = (_Float16)alpha;
  h2 al = {ah, ah};
  h2 r[4];
#pragma unroll
  for(int i = 0; i < 4; i++) r[i] = a[i] * al;
  size_t off = (size_t)node * stride + half * (C_HID/2) + l15 * 8;
  if(Pb){
    uint4 pv = *(const uint4*)(Pb + off);
    r[0] -= __builtin_bit_cast(h2, pv.x);
    r[1] -= __builtin_bit_cast(h2, pv.y);
    r[2] -= __builtin_bit_cast(h2, pv.z);
    r[3] -= __builtin_bit_cast(h2, pv.w);
  }
  uint4 ob;
  ob.x = __builtin_bit_cast(unsigned, r[0]);
  ob.y = __builtin_bit_cast(unsigned, r[1]);
  ob.z = __builtin_bit_cast(unsigned, r[2]);
  ob.w = __builtin_bit_cast(unsigned, r[3]);
  *(uint4*)(tx + off) = ob;
}

__global__ __launch_bounds__(256) void k_prop128(const _Float16* __restrict__ Xb,
                                                 const _Float16* __restrict__ Pb,
                                                 _Float16* __restrict__ tx,
                                                 const int* __restrict__ csr_s,
                                                 const unsigned* __restrict__ csr_wp,
                                                 const int* __restrict__ offs,
                                                 const int* __restrict__ perm,
                                                 float alpha){
  const int stride  = KCHEB * C_IN;      // 1280 elements
  const int strideB = stride * 2;        // 2560 bytes
  int hl   = threadIdx.x & 31;
  int b32  = threadIdx.x & 32;
  int e8   = hl & 7;
  int node = perm[blockIdx.x * 8 + (threadIdx.x >> 5)];
  int j0 = offs[node], j1 = offs[node + 1];
  h2 a[2] = {};
  const char* __restrict__ gbase = (const char*)Xb + hl * 8;
  int j = j0;
  int sv = 0; unsigned wv = 0;
  bool have = (j + 7 < j1);
  if(have){ sv = csr_s[j + e8] * strideB; wv = csr_wp[j + e8]; }
  while(have){
    int jn = j + 8;
    bool more = (jn + 7 < j1);
    int sv2 = 0; unsigned wv2 = 0;
    if(more){ sv2 = csr_s[jn + e8] * strideB; wv2 = csr_wp[jn + e8]; }
    uint2 v[8];
#pragma unroll
    for(int i = 0; i < 8; i++){
      int si = __shfl(sv, b32 + i);
      v[i] = *(const uint2*)(gbase + si);
    }
#pragma unroll
    for(int i = 0; i < 8; i++){
      unsigned wi = (unsigned)__shfl((int)wv, b32 + i);
      h2 w2 = __builtin_bit_cast(h2, wi);
      a[0] += __builtin_bit_cast(h2, v[i].x) * w2;
      a[1] += __builtin_bit_cast(h2, v[i].y) * w2;
    }
    sv = sv2; wv = wv2; j = jn; have = more;
  }
  for(; j < j1; j++){
    int si = csr_s[j] * strideB;
    h2 w2 = __builtin_bit_cast(h2, csr_wp[j]);
    uint2 v0 = *(const uint2*)(gbase + si);
    a[0] += __builtin_bit_cast(h2, v0.x) * w2;
    a[1] += __builtin_bit_cast(h2, v0.y) * w2;
  }
  _Float16 ah = (_Float16)alpha;
  h2 al = {ah, ah};
  h2 r0 = a[0] * al, r1 = a[1] * al;
  size_t off = (size_t)node * stride + hl * 4;
  if(Pb){
    uint2 pv = *(const uint2*)(Pb + off);
    r0 -= __builtin_bit_cast(h2, pv.x);
    r1 -= __builtin_bit_cast(h2, pv.y);
  }
  uint2 ob;
  ob.x = __builtin_bit_cast(unsigned, r0);
  ob.y = __builtin_bit_cast(unsigned, r1);
  *(uint2*)(tx + off) = ob;
}

// ---------------- fused prep: weight transposes + x->f16 ----------------
__global__ __launch_bounds__(256) void k_prep(const float* __restrict__ W0, _Float16* __restrict__ WT0,
                                              const float* __restrict__ W1, _Float16* __restrict__ WT1,
                                              const float* __restrict__ W2, _Float16* __restrict__ WT2,
                                              const float* __restrict__ X, _Float16* __restrict__ txP){
  int b = blockIdx.x;
  if(b >= 1600){
    int idx = (b - 1600) * 256 + threadIdx.x;
    if(idx < N_NODES * (C_IN / 4)){
      int r = idx >> 5;                 // C_IN/4 = 32
      int c = (idx & 31) * 4;
      float4 v = *(const float4*)(X + (size_t)r * C_IN + c);
      h2 p0 = {(_Float16)v.x, (_Float16)v.y};
      h2 p1 = {(_Float16)v.z, (_Float16)v.w};
      uint2 ob;
      ob.x = __builtin_bit_cast(unsigned, p0);
      ob.y = __builtin_bit_cast(unsigned, p1);
      *(uint2*)(txP + (size_t)r * (KCHEB * C_IN) + c) = ob;
    }
    return;
  }
  __shared__ float t[32][33];
  const float* W; _Float16* WT; int R; int tb;
  if(b < 320){ W = W0; WT = WT0; R = 1280; tb = b; }
  else if(b < 960){ W = W1; WT = WT1; R = 2560; tb = b - 320; }
  else { W = W2; WT = WT2; R = 2560; tb = b - 960; }
  int tr = tb >> 3, tc = tb & 7;
  int tx = threadIdx.x & 31, ty = threadIdx.x >> 5;
#pragma unroll
  for(int i = 0; i < 4; i++){
    int r = tr * 32 + ty + 8 * i;
    t[ty + 8 * i][tx] = W[(size_t)r * 256 + tc * 32 + tx];
  }
  __syncthreads();
#pragma unroll
  for(int i = 0; i < 4; i++){
    int o = tc * 32 + ty + 8 * i;
    WT[(size_t)o * R + tr * 32 + tx] = (_Float16)t[tx][ty + 8 * i];
  }
}

// ---------------- MFMA GEMM (f16) 64x64, XCD-pinned, single-sync dbuf ------
// PROVEN shape: 640 blocks, 32KB LDS, 0 bank conflicts. Layer-3 path
// (tx2==null): pooled epilogue (LDS-stage ReLU tile, run-reduce, atomicAdd).

__global__ __launch_bounds__(256) void k_gemm_f(const _Float16* __restrict__ A,
                                                const _Float16* __restrict__ BT,
                                                const float* __restrict__ bias,
                                                _Float16* __restrict__ tx2,
                                                const int* __restrict__ batch,
                                                float* __restrict__ gsum,
                                                int M, int Ktot){
  int b = blockIdx.x;
  int xcd = b & 7;
  int l = b >> 3;
  int m = xcd + 8 * (l >> 2);
  int n = l & 3;
  if(m * 64 >= M) return;
  int row0 = m * 64, col0 = n * 64;

  __shared__ short As[2][64 * 64];
  __shared__ short Bs[2][64 * 64];
  int tid = threadIdx.x;
  int lane = tid & 63;
  int wave = tid >> 6;
  int l15 = lane & 15;
  int quad = lane >> 4;
  int wm = (wave & 1) * 32;
  int wn = (wave >> 1) * 32;

  int e0 = tid, e1 = tid + 256;
  int r0 = e0 >> 3, g0 = e0 & 7;
  int r1 = e1 >> 3, g1 = e1 & 7;
  int gr0 = row0 + r0, gr1 = row0 + r1;
  int sa0 = r0 * 64 + ((g0 ^ (r0 & 7)) * 8);
  int sa1 = r1 * 64 + ((g1 ^ (r1 & 7)) * 8);

  f32x4 acc[2][2] = {};
  uint4 av0, av1, bv0, bv1;

  auto load = [&](int k0){
    av0 = (gr0 < M) ? *(const uint4*)(A + (size_t)gr0 * Ktot + k0 + g0 * 8)
                    : make_uint4(0u, 0u, 0u, 0u);
    av1 = (gr1 < M) ? *(const uint4*)(A + (size_t)gr1 * Ktot + k0 + g1 * 8)
                    : make_uint4(0u, 0u, 0u, 0u);
    bv0 = *(const uint4*)(BT + (size_t)(col0 + r0) * Ktot + k0 + g0 * 8);
    bv1 = *(const uint4*)(BT + (size_t)(col0 + r1) * Ktot + k0 + g1 * 8);
  };
  auto stor = [&](int buf){
    *(uint4*)(&As[buf][sa0]) = av0;
    *(uint4*)(&As[buf][sa1]) = av1;
    *(uint4*)(&Bs[buf][sa0]) = bv0;
    *(uint4*)(&Bs[buf][sa1]) = bv1;
  };

  load(0);
  stor(0);
  __syncthreads();
  int nk = Ktot >> 6;
  for(int it = 0; it < nk; it++){
    int cur = it & 1;
    if(it + 1 < nk) load((it + 1) << 6);   // in flight across MFMAs
#pragma unroll
    for(int kk = 0; kk < 64; kk += 32){
      int g = (kk >> 3) + quad;
      half8 a[2], bb[2];
#pragma unroll
      for(int mi = 0; mi < 2; mi++){
        int r = wm + mi * 16 + l15;
        a[mi] = *(const half8*)(&As[cur][r * 64 + ((g ^ (r & 7)) * 8)]);
      }
#pragma unroll
      for(int ni = 0; ni < 2; ni++){
        int nn = wn + ni * 16 + l15;
        bb[ni] = *(const half8*)(&Bs[cur][nn * 64 + ((g ^ (nn & 7)) * 8)]);
      }
#pragma unroll
      for(int mi = 0; mi < 2; mi++)
#pragma unroll
        for(int ni = 0; ni < 2; ni++)
          acc[mi][ni] = __builtin_amdgcn_mfma_f32_16x16x32_f16(a[mi], bb[ni], acc[mi][ni], 0, 0, 0);
    }
    if(it + 1 < nk){
      stor(cur ^ 1);
      __syncthreads();
    }
  }

  if(tx2){
    const int K256 = KCHEB * C_HID;
#pragma unroll
    for(int mi = 0; mi < 2; mi++){
#pragma unroll
      for(int ni = 0; ni < 2; ni++){
        int gcol = col0 + wn + ni * 16 + l15;
        float bv = bias[gcol];
#pragma unroll
        for(int r = 0; r < 4; r++){
          int grow = row0 + wm + mi * 16 + quad * 4 + r;
          if(grow < M){
            float v = fmaxf(acc[mi][ni][r] + bv, 0.f);
            tx2[(size_t)grow * K256 + gcol] = (_Float16)v;
          }
        }
      }
    }
  } else {
    // pooled epilogue (layer 3)
    __syncthreads();
    float* Ls = (float*)As;                // 16 KB
#pragma unroll
    for(int mi = 0; mi < 2; mi++){
#pragma unroll
      for(int ni = 0; ni < 2; ni++){
        int lc = wn + ni * 16 + l15;
        float bv = bias[col0 + lc];
#pragma unroll
        for(int r = 0; r < 4; r++){
          int lr = wm + mi * 16 + quad * 4 + r;
          Ls[lr * 64 + lc] = fmaxf(acc[mi][ni][r] + bv, 0.f);
        }
      }
    }
    __syncthreads();
    int col  = tid & 63;
    int rseg = tid >> 6;
    int rb   = rseg * 16;
    float accp = 0.f;
    int curg = -1;
    for(int rr = 0; rr < 16; rr++){
      int grow = row0 + rb + rr;
      if(grow >= M) break;
      int g = batch[grow];
      if(g != curg){
        if(curg >= 0) atomicAdd(&gsum[curg * C_HID + col0 + col], accp);
        accp = 0.f; curg = g;
      }
      accp += Ls[(rb + rr) * 64 + col];
    }
    if(curg >= 0) atomicAdd(&gsum[curg * C_HID + col0 + col], accp);
  }
}

// ---------------- head ----------------

__global__ __launch_bounds__(128) void k_final(const float* __restrict__ gsum,
                                               const int* __restrict__ gcnt,
                                               const float* __restrict__ Wout,
                                               const float* __restrict__ bout,
                                               float* __restrict__ out){
  int g = blockIdx.x;
  int o = threadIdx.x;
  float inv = 1.f / fmaxf((float)gcnt[g], 1.f);
  float acc = bout[o];
  for(int c = 0; c < C_HID; c++) acc += gsum[g * C_HID + c] * inv * Wout[c * C_OUTC + o];
  out[g * C_OUTC + o] = acc;
}

// ---------------- host ----------------

extern "C" void kernel_launch(void* const* d_in, const int* in_sizes, int n_in,
                              void* d_out, int out_size, void* d_ws, size_t ws_size,
                              hipStream_t stream){
  const float* x    = (const float*)d_in[0];
  const float* W0   = (const float*)d_in[1];
  const float* b0   = (const float*)d_in[2];
  const float* W1   = (const float*)d_in[3];
  const float* b1   = (const float*)d_in[4];
  const float* W2   = (const float*)d_in[5];
  const float* b2   = (const float*)d_in[6];
  const float* Wout = (const float*)d_in[7];
  const float* bout = (const float*)d_in[8];
  const int*   ei   = (const int*)d_in[9];
  const int*   batch= (const int*)d_in[10];
  const int* src = ei;
  const int* dst = ei + N_EDGES;
  float* out = (float*)d_out;

  char* p = (char*)d_ws;
  auto alloc = [&](size_t bytes)->char*{ char* r = p; p += align_up(bytes, 256); return r; };

  int*   deg    = (int*)  alloc(N_NODES * 4);
  int*   indeg  = (int*)  alloc(N_NODES * 4);
  int*   offs   = (int*)  alloc((N_NODES + 1) * 4);
  int*   cursor = (int*)  alloc(N_NODES * 4);
  float* dis    = (float*)alloc(N_NODES * 4);
  int*   perm   = (int*)  alloc(N_NODES * 4);
  int*   csr_s  = (int*)  alloc(N_EDGES * 4);
  unsigned* csr_wp = (unsigned*)alloc(N_EDGES * 4);
  int*   gcnt   = (int*)  alloc(N_GRAPHS * 4);
  int*   gstart = (int*)  alloc((N_GRAPHS + 1) * 4);
  float* gsum   = (float*)alloc(N_GRAPHS * C_HID * 4);

  const size_t txBytes = (size_t)N_NODES * (KCHEB * C_HID) * 2;  // 51.2 MB
  _Float16* txP = (_Float16*)alloc(txBytes);
  _Float16* txQ = (_Float16*)alloc(txBytes);
  _Float16* WT0 = (_Float16*)alloc((size_t)KCHEB * C_IN  * C_HID * 2);
  _Float16* WT1 = (_Float16*)alloc((size_t)KCHEB * C_HID * C_HID * 2);
  _Float16* WT2 = (_Float16*)alloc((size_t)KCHEB * C_HID * C_HID * 2);

  hipMemsetAsync(deg,   0, N_NODES * 4, stream);
  hipMemsetAsync(indeg, 0, N_NODES * 4, stream);
  hipMemsetAsync(gsum,  0, N_GRAPHS * C_HID * 4, stream);

  const int TB = 256;
  int egrid = (N_EDGES + TB - 1) / TB;

  k_deg<<<egrid, TB, 0, stream>>>(src, dst, deg, indeg);
  k_scan<<<1, 1024, 0, stream>>>(indeg, offs, cursor, deg, dis, perm, batch, gstart, gcnt);
  k_scatter<<<egrid, TB, 0, stream>>>(src, dst, dis, cursor, csr_s, csr_wp);
  k_prep<<<2850, 256, 0, stream>>>(W0, WT0, W1, WT1, W2, WT2, x, txP);

  const int K128 = KCHEB * C_IN;   // 1280
  const int K256 = KCHEB * C_HID;  // 2560
  const int GEMM_BLOCKS = 640;
  const int PROP_H_BLOCKS = 1256;
  const int PROP_1_BLOCKS = N_NODES / 8;  // 1250

  // ---- layer 1 ----
  {
    for(int k = 1; k < KCHEB; k++){
      const _Float16* Xb = txP + (size_t)(k - 1) * C_IN;
      const _Float16* Pb = (k >= 2) ? txP + (size_t)(k - 2) * C_IN : nullptr;
      _Float16* tx = txP + (size_t)k * C_IN;
      k_prop128<<<PROP_1_BLOCKS, 256, 0, stream>>>(Xb, Pb, tx, csr_s, csr_wp, offs, perm,
                                                   k == 1 ? 1.f : 2.f);
    }
    k_gemm_f<<<GEMM_BLOCKS, 256, 0, stream>>>(txP, WT0, b0, txQ, nullptr, nullptr,
                                              N_NODES, K128);
  }

  // ---- layer 2 ----
  {
    for(int k = 1; k < KCHEB; k++){
      const _Float16* Xb = txQ + (size_t)(k - 1) * C_HID;
      const _Float16* Pb = (k >= 2) ? txQ + (size_t)(k - 2) * C_HID : nullptr;
      _Float16* tx = txQ + (size_t)k * C_HID;
      k_prop256h<<<PROP_H_BLOCKS, 256, 0, stream>>>(Xb, Pb, tx, csr_s, csr_wp, offs, perm,
                                                    k == 1 ? 1.f : 2.f);
    }
    k_gemm_f<<<GEMM_BLOCKS, 256, 0, stream>>>(txQ, WT1, b1, txP, nullptr, nullptr,
                                              N_NODES, K256);
  }

  // ---- layer 3 ----
  {
    for(int k = 1; k < KCHEB; k++){
      const _Float16* Xb = txP + (size_t)(k - 1) * C_HID;
      const _Float16* Pb = (k >= 2) ? txP + (size_t)(k - 2) * C_HID : nullptr;
      _Float16* tx = txP + (size_t)k * C_HID;
      k_prop256h<<<PROP_H_BLOCKS, 256, 0, stream>>>(Xb, Pb, tx, csr_s, csr_wp, offs, perm,
                                                    k == 1 ? 1.f : 2.f);
    }
    k_gemm_f<<<GEMM_BLOCKS, 256, 0, stream>>>(txP, WT2, b2, nullptr, batch, gsum,
                                              N_NODES, K256);
  }

  k_final<<<N_GRAPHS, C_OUTC, 0, stream>>>(gsum, gcnt, Wout, bout, out);
}